// Round 10
// baseline (126.363 us; speedup 1.0000x reference)
//
#include <hip/hip_runtime.h>

// DigitCaps dynamic routing — 4 blocks per batch (hw-quarters), fence-free
// cross-block exchange via agent-scope atomics (round-9 proven: passed at
// absmax 4.9e-4 with WRITE=656KB -> no fence storms, no spill).
// Round-9 lesson: dur invariant at ~44us despite halving per-block work ->
//   stall-dominated per wave; VALU busy-time constant ~9us across rounds.
//   Only 2 waves/SIMD were resident (1 block/CU). This round: 512 blocks =
//   2 blocks/CU = 4 waves/SIMD (VGPR 120x4=480<=512 exactly fits).
// Round-3/6/7 lesson: 512-thr blocks have a hard 128-VGPR budget; o-split
//   heavy map (wv[5][8]+tl[5][8], shfl_xor(.,1) coupling) fits: VGPR=120.
// Co-residency (spin safety): LDS 23KB -> 6 blk/CU; launch_bounds(512,2)
//   -> 2 blk/CU x 256 CU = 512 = grid. All participants resident.
//
// Block (bq,b) owns hw in [bq*36, bq*36+36), all 32 c. Only 160-float
// s-partials cross blocks (3 syncs/launch, monotone tickets, replay-safe).

#define BB 128
#define CC 32
#define HWN 144   // 12*12
#define NSP 4     // hw splits per batch
#define HWQ 36    // per-block hw quarter
#define QQ 8      // IN_CAPS
#define OO 10     // OUT_CH
#define PP 16     // OUT_CAPS
#define OH 5      // o's per lane-half

__device__ float    g_sx[3 * BB * NSP * OO * PP];  // [phase][b][bq][160]
__device__ unsigned g_cnt[BB * 32];                // per-batch tickets, 128B stride

__device__ __forceinline__ float squash16(float s) {
    // tid = o*16 + p : reduce s^2 over the 16 p-lanes (masks 1..8)
    float sn = s * s;
#pragma unroll
    for (int m = 1; m <= 8; m <<= 1) sn += __shfl_xor(sn, m);
    return s * (sqrtf(sn) / (1.f + sn));
}

__global__ __launch_bounds__(512, 2)
void digitcaps_routing(const float* __restrict__ x, const float* __restrict__ Wm,
                       float* __restrict__ out) {
    const int bq  = blockIdx.x;   // 0..3 hw quarter
    const int b   = blockIdx.y;   // 0..127
    const int tid = threadIdx.x;

    __shared__ float usum_s[CC * QQ];        // 1 KB   (partial over this quarter)
    __shared__ float Wv_s[CC * OO * QQ];     // 10 KB  (running logit-weight acc)
    __shared__ float t_s[CC * OO * QQ];      // 10 KB  (partial over this quarter)
    __shared__ float v_s[OO * PP];           // 640 B
    __shared__ float ps2_s[2 * OO * PP];     // 1.25 KB (cc-half partials)

    // ---- A: usum[c][q] = sum_{hw in quarter} x[b,c,hw,q] ----
    {
        const int c = tid >> 4, slot = tid & 15;
        const float* xc = x + (((size_t)b * CC + c) * HWN + bq * HWQ) * QQ;
        float us[QQ];
#pragma unroll
        for (int q = 0; q < QQ; ++q) us[q] = 0.f;
#pragma unroll
        for (int i = 0; i < 3; ++i) {        // 36 = 16 slots * 2.25
            const int hwl = slot + (i << 4);
            if (hwl < HWQ) {
                const float4* p4 = (const float4*)(xc + hwl * QQ);
                float4 a = p4[0], d = p4[1];
                us[0] += a.x; us[1] += a.y; us[2] += a.z; us[3] += a.w;
                us[4] += d.x; us[5] += d.y; us[6] += d.z; us[7] += d.w;
            }
        }
#pragma unroll
        for (int m = 1; m <= 8; m <<= 1) {
#pragma unroll
            for (int q = 0; q < QQ; ++q) us[q] += __shfl_xor(us[q], m);
        }
        if (slot == 0) {
#pragma unroll
            for (int q = 0; q < QQ; ++q) usum_s[c * QQ + q] = us[q];
        }
    }
    __syncthreads();

    // heavy-phase thread map (fixed for the whole kernel)
    const int hc    = tid >> 4;          // 0..31
    const int hslot = (tid >> 1) & 7;    // 0..7
    const int oh    = tid & 1;           // 0..1
    const int obase = oh * OH;
    const float* xhc = x + (((size_t)b * CC + hc) * HWN + bq * HWQ) * QQ;

    // ---- 3 phases: ph=0 -> v1 seed; ph=1,2 -> routing iters ----
    for (int ph = 0; ph < 3; ++ph) {
        // local partial s[o,p], split over 2 cc-halves (320 threads)
        if (tid < 2 * OO * PP) {
            const int h   = tid >= OO * PP;
            const int idx = h ? tid - OO * PP : tid;
            const int o = idx >> 4, p = idx & 15;
            const int c0 = h * 16;
            float s = 0.f;
#pragma unroll
            for (int k = 0; k < 16; ++k) {
                const int cc = c0 + k;
                const float4* w4 = (const float4*)(Wm + (((cc * OO + o) * PP + p) * QQ));
                float4 w0 = w4[0], w1 = w4[1];
                const float* src = (ph == 0) ? &usum_s[cc * QQ]
                                             : &t_s[(cc * OO + o) * QQ];
                s += w0.x * src[0] + w0.y * src[1] + w0.z * src[2] + w0.w * src[3]
                   + w1.x * src[4] + w1.y * src[5] + w1.z * src[6] + w1.w * src[7];
            }
            ps2_s[tid] = s;
        }
        __syncthreads();

        // ---- exchange 160-float s-partial with the 3 partner blocks ----
        const int spin = (ph < 2) ? 1 : (bq == 0);
        float sown = 0.f;
        if (tid < OO * PP) {
            sown = ps2_s[tid] + ps2_s[OO * PP + tid];
            __hip_atomic_store(&g_sx[(((size_t)ph * BB + b) * NSP + bq) * (OO * PP) + tid],
                               sown, __ATOMIC_RELAXED, __HIP_MEMORY_SCOPE_AGENT);
        }
        __syncthreads();   // drains vmcnt(0): stores are at the coherent point
        if (tid == 0) {
            unsigned t = __hip_atomic_fetch_add(&g_cnt[b * 32], 1u,
                             __ATOMIC_RELAXED, __HIP_MEMORY_SCOPE_AGENT);
            if (spin) {
                const unsigned target = (t / NSP + 1u) * NSP;
                while (__hip_atomic_load(&g_cnt[b * 32], __ATOMIC_RELAXED,
                                         __HIP_MEMORY_SCOPE_AGENT) < target)
                    __builtin_amdgcn_s_sleep(1);
            }
        }
        __syncthreads();
        if (!spin) break;  // bq>0 at ph==2: posted, done (no output to write)

        // combine partials -> v (or final output)
        if (tid < OO * PP) {
            float s = sown;
#pragma unroll
            for (int g = 0; g < NSP; ++g) {
                if (g == bq) continue;
                s += __hip_atomic_load(
                    &g_sx[(((size_t)ph * BB + b) * NSP + g) * (OO * PP) + tid],
                    __ATOMIC_RELAXED, __HIP_MEMORY_SCOPE_AGENT);
            }
            if (ph == 0) s *= 0.1f;          // iter-1 uniform c_ij
            const float v = squash16(s);
            if (ph == 2) { out[(size_t)b * (OO * PP) + tid] = v; }
            else         { v_s[tid] = v; }
        }
        if (ph == 2) break;
        __syncthreads();

        // ---- Wv (set on ph0, accumulate on ph1): Wv += Wm . v ----
        if (tid < CC * OO) {
            const int cc = tid / OO, o = tid - cc * OO;
            float acc[QQ];
#pragma unroll
            for (int q = 0; q < QQ; ++q) acc[q] = 0.f;
            const float* wp = Wm + ((cc * OO + o) * PP) * QQ;
#pragma unroll
            for (int p = 0; p < PP; ++p) {
                const float vv = v_s[o * PP + p];
                const float4* w4 = (const float4*)(wp + p * QQ);
                float4 w0 = w4[0], w1 = w4[1];
                acc[0] += vv * w0.x; acc[1] += vv * w0.y; acc[2] += vv * w0.z; acc[3] += vv * w0.w;
                acc[4] += vv * w1.x; acc[5] += vv * w1.y; acc[6] += vv * w1.z; acc[7] += vv * w1.w;
            }
            float* dst = Wv_s + (cc * OO + o) * QQ;
            if (ph == 0) {
#pragma unroll
                for (int q = 0; q < QQ; ++q) dst[q] = acc[q];
            } else {
#pragma unroll
                for (int q = 0; q < QQ; ++q) dst[q] += acc[q];
            }
        }
        __syncthreads();

        // ---- heavy: logits = u.Wv, softmax over o, t = sum_hw c_ij*u ----
        float wv[OH][QQ];
#pragma unroll
        for (int j = 0; j < OH; ++j)
#pragma unroll
            for (int q = 0; q < QQ; ++q)
                wv[j][q] = Wv_s[(hc * OO + obase + j) * QQ + q];

        float tl[OH][QQ];
#pragma unroll
        for (int j = 0; j < OH; ++j)
#pragma unroll
            for (int q = 0; q < QQ; ++q) tl[j][q] = 0.f;

#pragma unroll
        for (int i = 0; i < 5; ++i) {        // 36 = 8 slots * 4.5
            const int hwl = hslot + (i << 3);
            if (hwl < HWQ) {
                const float4* p4 = (const float4*)(xhc + hwl * QQ);
                float4 a = p4[0], d = p4[1];
                float u[QQ] = {a.x, a.y, a.z, a.w, d.x, d.y, d.z, d.w};
                float lg[OH];
#pragma unroll
                for (int j = 0; j < OH; ++j) {
                    float t = 0.f;
#pragma unroll
                    for (int q = 0; q < QQ; ++q) t += u[q] * wv[j][q];
                    lg[j] = t;
                }
                float pm = fmaxf(fmaxf(fmaxf(lg[0], lg[1]), fmaxf(lg[2], lg[3])), lg[4]);
                pm = fmaxf(pm, __shfl_xor(pm, 1));
                float psum = 0.f;
#pragma unroll
                for (int j = 0; j < OH; ++j) { lg[j] = __expf(lg[j] - pm); psum += lg[j]; }
                psum += __shfl_xor(psum, 1);
                const float inv = 1.f / psum;
#pragma unroll
                for (int j = 0; j < OH; ++j) {
                    const float cij = lg[j] * inv;
#pragma unroll
                    for (int q = 0; q < QQ; ++q) tl[j][q] += cij * u[q];
                }
            }
        }
        // reduce t over the 8 slot lanes (masks 2,4,8; oh stays separate)
#pragma unroll
        for (int m = 2; m <= 8; m <<= 1) {
#pragma unroll
            for (int j = 0; j < OH; ++j)
#pragma unroll
                for (int q = 0; q < QQ; ++q) tl[j][q] += __shfl_xor(tl[j][q], m);
        }
        if (hslot == 0) {
#pragma unroll
            for (int j = 0; j < OH; ++j)
#pragma unroll
                for (int q = 0; q < QQ; ++q)
                    t_s[(hc * OO + obase + j) * QQ + q] = tl[j][q];
        }
        __syncthreads();
    }
}

extern "C" void kernel_launch(void* const* d_in, const int* in_sizes, int n_in,
                              void* d_out, int out_size, void* d_ws, size_t ws_size,
                              hipStream_t stream) {
    const float* x  = (const float*)d_in[0];   // [128,32,12,12,8]
    const float* Wm = (const float*)d_in[1];   // [1,1,32,10,16,8]
    float* out      = (float*)d_out;           // [128,10,16]
    digitcaps_routing<<<dim3(NSP, BB), 512, 0, stream>>>(x, Wm, out);
}

// Round 11
// 95.236 us; speedup vs baseline: 1.3268x; 1.3268x over previous
//
#include <hip/hip_runtime.h>

// DigitCaps dynamic routing — 2 blocks per batch (hw-halves), fence-free
// cross-block exchange via agent-scope atomics. Polished round-9 optimum.
// Round-10 lesson: per-sync cost grows superlinearly with participants
//   (2-way ~4us, 4-way ~13us) -> 2 blocks/batch is the sweet spot; do NOT
//   split further. This round: shave the round-9 structure instead:
//   (a) syncs 3->2: compute FULL usum redundantly in both partners (~1us)
//       instead of exchanging it (~5us);
//   (b) defer-max softmax: logits are bounded (|b_ij|<~30) so exp without
//       max-subtraction is fp32-safe and identical -> deletes the max tree
//       + one shfl_xor from the per-hw serial chain (the stall driver);
//   (c) grid (128,2): partner blocks' linear IDs differ by 128 = 0 mod 8
//       -> same XCD -> faster ticket/data visibility.
// Round-3/6/7 lesson: 512-thr blocks have a hard 128-VGPR budget; o-split
//   heavy map (wv[5][8]+tl[5][8], shfl_xor(.,1) coupling) fits: VGPR~112.
// Tickets: monotone, 4 increments/batch/launch -> graph-replay safe.

#define BB 128
#define CC 32
#define HWN 144   // 12*12
#define HWH 72    // per-block hw half
#define QQ 8      // IN_CAPS
#define OO 10     // OUT_CH
#define PP 16     // OUT_CAPS
#define OH 5      // o's per lane-half

__device__ float    g_sx[2 * BB * 2 * OO * PP];  // [it][b][bh][160]
__device__ unsigned g_cnt[BB * 32];              // per-batch tickets, 128B stride

__device__ __forceinline__ float squash16(float s) {
    // tid = o*16 + p : reduce s^2 over the 16 p-lanes (masks 1..8)
    float sn = s * s;
#pragma unroll
    for (int m = 1; m <= 8; m <<= 1) sn += __shfl_xor(sn, m);
    return s * (sqrtf(sn) / (1.f + sn));
}

__global__ __launch_bounds__(512, 1)
void digitcaps_routing(const float* __restrict__ x, const float* __restrict__ Wm,
                       float* __restrict__ out) {
    const int b   = blockIdx.x;   // 0..127
    const int bh  = blockIdx.y;   // 0..1 hw half (partner = same XCD)
    const int tid = threadIdx.x;

    __shared__ float usum_s[CC * QQ];        // 1 KB   (FULL-range usum)
    __shared__ float Wv_s[CC * OO * QQ];     // 10 KB  (running logit-weight acc)
    __shared__ float t_s[CC * OO * QQ];      // 10 KB  (partial over this half)
    __shared__ float v_s[OO * PP];           // 640 B
    __shared__ float ps2_s[2 * OO * PP];     // 1.25 KB (cc-half partials)

    // ---- A: FULL usum[c][q] = sum_hw x[b,c,hw,q] (redundant per partner) ----
    {
        const int c = tid >> 4, slot = tid & 15;
        const float* xc = x + ((size_t)b * CC + c) * (HWN * QQ);
        float us[QQ];
#pragma unroll
        for (int q = 0; q < QQ; ++q) us[q] = 0.f;
#pragma unroll
        for (int i = 0; i < 9; ++i) {        // 144 = 16 slots * 9
            const int hw = slot + (i << 4);
            const float4* p4 = (const float4*)(xc + hw * QQ);
            float4 a = p4[0], d = p4[1];
            us[0] += a.x; us[1] += a.y; us[2] += a.z; us[3] += a.w;
            us[4] += d.x; us[5] += d.y; us[6] += d.z; us[7] += d.w;
        }
#pragma unroll
        for (int m = 1; m <= 8; m <<= 1) {
#pragma unroll
            for (int q = 0; q < QQ; ++q) us[q] += __shfl_xor(us[q], m);
        }
        if (slot == 0) {
#pragma unroll
            for (int q = 0; q < QQ; ++q) usum_s[c * QQ + q] = us[q];
        }
    }
    __syncthreads();

    // ---- B: s1 = 0.1 * Wm . usum (2-half cc split); v1 = squash(s1) ----
    if (tid < 2 * OO * PP) {
        const int h   = tid >= OO * PP;
        const int idx = h ? tid - OO * PP : tid;
        const int o = idx >> 4, p = idx & 15;
        const int c0 = h * 16;
        float s = 0.f;
#pragma unroll
        for (int k = 0; k < 16; ++k) {
            const int cc = c0 + k;
            const float4* w4 = (const float4*)(Wm + (((cc * OO + o) * PP + p) * QQ));
            float4 w0 = w4[0], w1 = w4[1];
            const float* u0 = &usum_s[cc * QQ];
            s += w0.x * u0[0] + w0.y * u0[1] + w0.z * u0[2] + w0.w * u0[3]
               + w1.x * u0[4] + w1.y * u0[5] + w1.z * u0[6] + w1.w * u0[7];
        }
        ps2_s[tid] = s;
    }
    __syncthreads();
    if (tid < OO * PP)
        v_s[tid] = squash16(0.1f * (ps2_s[tid] + ps2_s[OO * PP + tid]));
    __syncthreads();

    // ---- Wv = Wm . v1 ----
    if (tid < CC * OO) {
        const int cc = tid / OO, o = tid - cc * OO;
        float acc[QQ];
#pragma unroll
        for (int q = 0; q < QQ; ++q) acc[q] = 0.f;
        const float* wp = Wm + ((cc * OO + o) * PP) * QQ;
#pragma unroll
        for (int p = 0; p < PP; ++p) {
            const float vv = v_s[o * PP + p];
            const float4* w4 = (const float4*)(wp + p * QQ);
            float4 w0 = w4[0], w1 = w4[1];
            acc[0] += vv * w0.x; acc[1] += vv * w0.y; acc[2] += vv * w0.z; acc[3] += vv * w0.w;
            acc[4] += vv * w1.x; acc[5] += vv * w1.y; acc[6] += vv * w1.z; acc[7] += vv * w1.w;
        }
        float* dst = Wv_s + (cc * OO + o) * QQ;
#pragma unroll
        for (int q = 0; q < QQ; ++q) dst[q] = acc[q];
    }
    __syncthreads();

    // heavy-phase thread map
    const int hc    = tid >> 4;          // 0..31
    const int hslot = (tid >> 1) & 7;    // 0..7
    const int oh    = tid & 1;           // 0..1
    const int obase = oh * OH;
    const float* xhc = x + (((size_t)b * CC + hc) * HWN + bh * HWH) * QQ;

    // ---- routing iterations (it=0 -> iter2, it=1 -> iter3) ----
    for (int it = 0; it < 2; ++it) {
        // heavy: logits = u.Wv, DEFER-MAX softmax over o, t = sum_hw c_ij*u
        float wv[OH][QQ];
#pragma unroll
        for (int j = 0; j < OH; ++j)
#pragma unroll
            for (int q = 0; q < QQ; ++q)
                wv[j][q] = Wv_s[(hc * OO + obase + j) * QQ + q];

        float tl[OH][QQ];
#pragma unroll
        for (int j = 0; j < OH; ++j)
#pragma unroll
            for (int q = 0; q < QQ; ++q) tl[j][q] = 0.f;

#pragma unroll 3
        for (int i = 0; i < 9; ++i) {        // 72 = 8 slots * 9
            const int hwl = hslot + (i << 3);
            const float4* p4 = (const float4*)(xhc + hwl * QQ);
            float4 a = p4[0], d = p4[1];
            float u[QQ] = {a.x, a.y, a.z, a.w, d.x, d.y, d.z, d.w};
            float lg[OH];
#pragma unroll
            for (int j = 0; j < OH; ++j) {
                float t = 0.f;
#pragma unroll
                for (int q = 0; q < QQ; ++q) t += u[q] * wv[j][q];
                lg[j] = __expf(t);           // defer-max: logits bounded, fp32-safe
            }
            float psum = ((lg[0] + lg[1]) + (lg[2] + lg[3])) + lg[4];
            psum += __shfl_xor(psum, 1);
            const float inv = 1.f / psum;
#pragma unroll
            for (int j = 0; j < OH; ++j) {
                const float cij = lg[j] * inv;
#pragma unroll
                for (int q = 0; q < QQ; ++q) tl[j][q] += cij * u[q];
            }
        }
        // reduce t over the 8 slot lanes (masks 2,4,8; oh stays separate)
#pragma unroll
        for (int m = 2; m <= 8; m <<= 1) {
#pragma unroll
            for (int j = 0; j < OH; ++j)
#pragma unroll
                for (int q = 0; q < QQ; ++q) tl[j][q] += __shfl_xor(tl[j][q], m);
        }
        if (hslot == 0) {
#pragma unroll
            for (int j = 0; j < OH; ++j)
#pragma unroll
                for (int q = 0; q < QQ; ++q)
                    t_s[(hc * OO + obase + j) * QQ + q] = tl[j][q];
        }
        __syncthreads();

        // partial s[o,p] = sum_{c,q} Wm * t  (2-half cc split)
        if (tid < 2 * OO * PP) {
            const int h   = tid >= OO * PP;
            const int idx = h ? tid - OO * PP : tid;
            const int o = idx >> 4, p = idx & 15;
            const int c0 = h * 16;
            float s = 0.f;
#pragma unroll
            for (int k = 0; k < 16; ++k) {
                const int cc = c0 + k;
                const float4* w4 = (const float4*)(Wm + (((cc * OO + o) * PP + p) * QQ));
                float4 w0 = w4[0], w1 = w4[1];
                const float4* t4 = (const float4*)(t_s + (cc * OO + o) * QQ);
                float4 t0 = t4[0], t1 = t4[1];
                s += w0.x * t0.x + w0.y * t0.y + w0.z * t0.z + w0.w * t0.w
                   + w1.x * t1.x + w1.y * t1.y + w1.z * t1.z + w1.w * t1.w;
            }
            ps2_s[tid] = s;
        }
        __syncthreads();

        // ---- exchange 160-float s-partial with the partner block ----
        const int spin = (it == 0) ? 1 : (bh == 0);
        float sown = 0.f;
        if (tid < OO * PP) {
            sown = ps2_s[tid] + ps2_s[OO * PP + tid];
            __hip_atomic_store(&g_sx[(((size_t)it * BB + b) * 2 + bh) * (OO * PP) + tid],
                               sown, __ATOMIC_RELAXED, __HIP_MEMORY_SCOPE_AGENT);
        }
        __syncthreads();   // drains vmcnt(0): stores at the coherent point
        if (tid == 0) {
            unsigned t = __hip_atomic_fetch_add(&g_cnt[b * 32], 1u,
                             __ATOMIC_RELAXED, __HIP_MEMORY_SCOPE_AGENT);
            if (spin) {
                const unsigned target = (t / 2u + 1u) * 2u;
                while (__hip_atomic_load(&g_cnt[b * 32], __ATOMIC_RELAXED,
                                         __HIP_MEMORY_SCOPE_AGENT) < target)
                    __builtin_amdgcn_s_sleep(1);
            }
        }
        __syncthreads();
        if (!spin) return;   // bh1 at it==1: posted, done

        // combine partials -> v (or final output)
        if (tid < OO * PP) {
            float soth = __hip_atomic_load(
                &g_sx[(((size_t)it * BB + b) * 2 + (1 - bh)) * (OO * PP) + tid],
                __ATOMIC_RELAXED, __HIP_MEMORY_SCOPE_AGENT);
            const float v = squash16(sown + soth);
            if (it == 1) out[(size_t)b * (OO * PP) + tid] = v;
            else         v_s[tid] = v;
        }
        if (it == 1) return;
        __syncthreads();

        // ---- Wv += Wm . v2 ----
        if (tid < CC * OO) {
            const int cc = tid / OO, o = tid - cc * OO;
            float acc[QQ];
#pragma unroll
            for (int q = 0; q < QQ; ++q) acc[q] = 0.f;
            const float* wp = Wm + ((cc * OO + o) * PP) * QQ;
#pragma unroll
            for (int p = 0; p < PP; ++p) {
                const float vv = v_s[o * PP + p];
                const float4* w4 = (const float4*)(wp + p * QQ);
                float4 w0 = w4[0], w1 = w4[1];
                acc[0] += vv * w0.x; acc[1] += vv * w0.y; acc[2] += vv * w0.z; acc[3] += vv * w0.w;
                acc[4] += vv * w1.x; acc[5] += vv * w1.y; acc[6] += vv * w1.z; acc[7] += vv * w1.w;
            }
            float* dst = Wv_s + (cc * OO + o) * QQ;
#pragma unroll
            for (int q = 0; q < QQ; ++q) dst[q] += acc[q];
        }
        __syncthreads();
    }
}

extern "C" void kernel_launch(void* const* d_in, const int* in_sizes, int n_in,
                              void* d_out, int out_size, void* d_ws, size_t ws_size,
                              hipStream_t stream) {
    const float* x  = (const float*)d_in[0];   // [128,32,12,12,8]
    const float* Wm = (const float*)d_in[1];   // [1,1,32,10,16,8]
    float* out      = (float*)d_out;           // [128,10,16]
    digitcaps_routing<<<dim3(BB, 2), 512, 0, stream>>>(x, Wm, out);
}

// Round 12
// 92.290 us; speedup vs baseline: 1.3692x; 1.0319x over previous
//
#include <hip/hip_runtime.h>

// DigitCaps dynamic routing — 2 blocks per batch (c-split, 16 channels each),
// Wm half staged in LDS, fence-free cross-block exchange (r9/r11 proven).
// Round-11 decomposition: T_serial ~32us dominates (B/Wv/s phases re-reading
//   Wm from L2: 5 x 160KB/block at ~300cy latency, <=320 threads, lockstep).
//   Fix: c-split -> each block's Wm half = 80KB fits LDS; serial loops go
//   16->8 iters and read LDS; Wv/t_s halve; heavy work total unchanged
//   (16c x 144hw vs 32c x 72hw).
// Round-10 lesson: >2 sync participants is net-negative; keep 2.
// Round-3/6 lesson: 512-thr blocks have a hard 128-VGPR budget; o-split
//   heavy map (wv[5][8]+tl[5][8], shfl_xor(.,1) coupling) fits (~116).
// Spin safety: 92KB LDS -> 1 block/CU, grid 256 = #CUs -> all resident.
// Tickets monotone: 6 increments/batch/launch -> graph-replay safe.

#define BB 128
#define CC 32
#define CL 16     // channels per block
#define HWN 144   // 12*12
#define QQ 8      // IN_CAPS
#define OO 10     // OUT_CH
#define PP 16     // OUT_CAPS
#define OH 5      // o's per lane-half

__device__ float    g_sx[3 * BB * 2 * OO * PP];  // [ph][b][ch][160]
__device__ unsigned g_cnt[BB * 32];              // per-batch tickets, 128B stride

__device__ __forceinline__ float squash16(float s) {
    // tid = o*16 + p : reduce s^2 over the 16 p-lanes (masks 1..8)
    float sn = s * s;
#pragma unroll
    for (int m = 1; m <= 8; m <<= 1) sn += __shfl_xor(sn, m);
    return s * (sqrtf(sn) / (1.f + sn));
}

__global__ __launch_bounds__(512, 1)
void digitcaps_routing(const float* __restrict__ x, const float* __restrict__ Wm,
                       float* __restrict__ out) {
    const int b   = blockIdx.x;   // 0..127
    const int ch  = blockIdx.y;   // 0..1 c-half (partner +128 -> same XCD)
    const int tid = threadIdx.x;

    __shared__ float Wm_s[CL * OO * PP * QQ];   // 80 KB  (own Wm half)
    __shared__ float usum_s[CL * QQ];           // 512 B
    __shared__ float Wv_s[CL * OO * QQ];        // 5 KB   (logit-weight acc)
    __shared__ float t_s[CL * OO * QQ];         // 5 KB
    __shared__ float v_s[OO * PP];              // 640 B
    __shared__ float ps2_s[2 * OO * PP];        // 1.25 KB

    // ---- stage own Wm half into LDS (5120 float4 = 512 thr x 10) ----
    {
        const float4* src = (const float4*)(Wm + (size_t)ch * (CL * OO * PP * QQ));
        float4* dst = (float4*)Wm_s;
#pragma unroll
        for (int k = 0; k < 10; ++k) dst[tid + (k << 9)] = src[tid + (k << 9)];
    }

    // ---- A: usum[cl][q] = sum_hw x[b, ch*16+cl, hw, q] ----
    {
        const int c = tid >> 5, slot = tid & 31;   // 16 c x 32 slots
        const float* xc = x + ((size_t)b * CC + ch * CL + c) * (HWN * QQ);
        float us[QQ];
#pragma unroll
        for (int q = 0; q < QQ; ++q) us[q] = 0.f;
#pragma unroll
        for (int i = 0; i < 5; ++i) {              // 144 = 32*4.5
            const int hw = slot + (i << 5);
            if (hw < HWN) {
                const float4* p4 = (const float4*)(xc + hw * QQ);
                float4 a = p4[0], d = p4[1];
                us[0] += a.x; us[1] += a.y; us[2] += a.z; us[3] += a.w;
                us[4] += d.x; us[5] += d.y; us[6] += d.z; us[7] += d.w;
            }
        }
#pragma unroll
        for (int m = 1; m <= 16; m <<= 1) {        // reduce over 32 slot lanes
#pragma unroll
            for (int q = 0; q < QQ; ++q) us[q] += __shfl_xor(us[q], m);
        }
        if (slot == 0) {
#pragma unroll
            for (int q = 0; q < QQ; ++q) usum_s[c * QQ + q] = us[q];
        }
    }
    __syncthreads();

    // heavy-phase thread map: 16 c x 16 slots x 2 oh
    const int hc    = tid >> 5;          // 0..15 local c
    const int hslot = (tid >> 1) & 15;   // 0..15
    const int oh    = tid & 1;           // 0..1
    const int obase = oh * OH;
    const float* xhc = x + ((size_t)b * CC + ch * CL + hc) * (HWN * QQ);

    // ---- 3 phases: ph=0 -> v1 seed; ph=1,2 -> routing iters ----
    for (int ph = 0; ph < 3; ++ph) {
        // partial s[o,p] over own 16 c, split into 2 x 8-c halves (320 thr)
        if (tid < 2 * OO * PP) {
            const int h   = tid >= OO * PP;
            const int idx = h ? tid - OO * PP : tid;
            const int o = idx >> 4, p = idx & 15;
            const int c0 = h * 8;
            float s = 0.f;
#pragma unroll
            for (int k = 0; k < 8; ++k) {
                const int cc = c0 + k;
                const float4* w4 = (const float4*)(Wm_s + (((cc * OO + o) * PP + p) * QQ));
                float4 w0 = w4[0], w1 = w4[1];
                const float* src = (ph == 0) ? &usum_s[cc * QQ]
                                             : &t_s[(cc * OO + o) * QQ];
                s += w0.x * src[0] + w0.y * src[1] + w0.z * src[2] + w0.w * src[3]
                   + w1.x * src[4] + w1.y * src[5] + w1.z * src[6] + w1.w * src[7];
            }
            ps2_s[tid] = s;
        }
        __syncthreads();

        // ---- exchange 160-float s-partial with the partner block ----
        const int spin = (ph < 2) ? 1 : (ch == 0);
        float sown = 0.f;
        if (tid < OO * PP) {
            sown = ps2_s[tid] + ps2_s[OO * PP + tid];
            __hip_atomic_store(&g_sx[(((size_t)ph * BB + b) * 2 + ch) * (OO * PP) + tid],
                               sown, __ATOMIC_RELAXED, __HIP_MEMORY_SCOPE_AGENT);
        }
        __syncthreads();   // drains vmcnt(0): stores at the coherent point
        if (tid == 0) {
            unsigned t = __hip_atomic_fetch_add(&g_cnt[b * 32], 1u,
                             __ATOMIC_RELAXED, __HIP_MEMORY_SCOPE_AGENT);
            if (spin) {
                const unsigned target = (t / 2u + 1u) * 2u;
                while (__hip_atomic_load(&g_cnt[b * 32], __ATOMIC_RELAXED,
                                         __HIP_MEMORY_SCOPE_AGENT) < target)
                    __builtin_amdgcn_s_sleep(1);
            }
        }
        __syncthreads();
        if (!spin) return;   // ch1 at ph==2: posted, done

        // combine partials -> v (or final output)
        if (tid < OO * PP) {
            float soth = __hip_atomic_load(
                &g_sx[(((size_t)ph * BB + b) * 2 + (1 - ch)) * (OO * PP) + tid],
                __ATOMIC_RELAXED, __HIP_MEMORY_SCOPE_AGENT);
            float s = sown + soth;
            if (ph == 0) s *= 0.1f;          // iter-1 uniform c_ij
            const float v = squash16(s);
            if (ph == 2) { out[(size_t)b * (OO * PP) + tid] = v; }
            else         { v_s[tid] = v; }
        }
        if (ph == 2) return;
        __syncthreads();

        // ---- Wv (own c only; set on ph0, accumulate on ph1) ----
        if (tid < CL * OO) {
            const int cl = tid / OO, o = tid - cl * OO;
            float acc[QQ];
#pragma unroll
            for (int q = 0; q < QQ; ++q) acc[q] = 0.f;
            const float* wp = Wm_s + ((cl * OO + o) * PP) * QQ;
#pragma unroll
            for (int p = 0; p < PP; ++p) {
                const float vv = v_s[o * PP + p];
                const float4* w4 = (const float4*)(wp + p * QQ);
                float4 w0 = w4[0], w1 = w4[1];
                acc[0] += vv * w0.x; acc[1] += vv * w0.y; acc[2] += vv * w0.z; acc[3] += vv * w0.w;
                acc[4] += vv * w1.x; acc[5] += vv * w1.y; acc[6] += vv * w1.z; acc[7] += vv * w1.w;
            }
            float* dst = Wv_s + (cl * OO + o) * QQ;
            if (ph == 0) {
#pragma unroll
                for (int q = 0; q < QQ; ++q) dst[q] = acc[q];
            } else {
#pragma unroll
                for (int q = 0; q < QQ; ++q) dst[q] += acc[q];
            }
        }
        __syncthreads();

        // ---- heavy: logits = u.Wv, defer-max softmax, t = sum_hw c_ij*u ----
        float wv[OH][QQ];
#pragma unroll
        for (int j = 0; j < OH; ++j)
#pragma unroll
            for (int q = 0; q < QQ; ++q)
                wv[j][q] = Wv_s[(hc * OO + obase + j) * QQ + q];

        float tl[OH][QQ];
#pragma unroll
        for (int j = 0; j < OH; ++j)
#pragma unroll
            for (int q = 0; q < QQ; ++q) tl[j][q] = 0.f;

#pragma unroll 3
        for (int i = 0; i < 9; ++i) {        // 144 = 16 slots * 9
            const int hw = hslot + (i << 4);
            const float4* p4 = (const float4*)(xhc + hw * QQ);
            float4 a = p4[0], d = p4[1];
            float u[QQ] = {a.x, a.y, a.z, a.w, d.x, d.y, d.z, d.w};
            float lg[OH];
#pragma unroll
            for (int j = 0; j < OH; ++j) {
                float t = 0.f;
#pragma unroll
                for (int q = 0; q < QQ; ++q) t += u[q] * wv[j][q];
                lg[j] = __expf(t);           // defer-max: logits bounded, fp32-safe
            }
            float psum = ((lg[0] + lg[1]) + (lg[2] + lg[3])) + lg[4];
            psum += __shfl_xor(psum, 1);
            const float inv = 1.f / psum;
#pragma unroll
            for (int j = 0; j < OH; ++j) {
                const float cij = lg[j] * inv;
#pragma unroll
                for (int q = 0; q < QQ; ++q) tl[j][q] += cij * u[q];
            }
        }
        // reduce t over the 16 slot lanes (masks 2..16; oh bit0, c bit5 apart)
#pragma unroll
        for (int m = 2; m <= 16; m <<= 1) {
#pragma unroll
            for (int j = 0; j < OH; ++j)
#pragma unroll
                for (int q = 0; q < QQ; ++q) tl[j][q] += __shfl_xor(tl[j][q], m);
        }
        if (hslot == 0) {
#pragma unroll
            for (int j = 0; j < OH; ++j)
#pragma unroll
                for (int q = 0; q < QQ; ++q)
                    t_s[(hc * OO + obase + j) * QQ + q] = tl[j][q];
        }
        __syncthreads();
    }
}

extern "C" void kernel_launch(void* const* d_in, const int* in_sizes, int n_in,
                              void* d_out, int out_size, void* d_ws, size_t ws_size,
                              hipStream_t stream) {
    const float* x  = (const float*)d_in[0];   // [128,32,12,12,8]
    const float* Wm = (const float*)d_in[1];   // [1,1,32,10,16,8]
    float* out      = (float*)d_out;           // [128,10,16]
    digitcaps_routing<<<dim3(BB, 2), 512, 0, stream>>>(x, Wm, out);
}